// Round 1
// baseline (393.120 us; speedup 1.0000x reference)
//
#include <hip/hip_runtime.h>
#include <stdint.h>

typedef __bf16          bf16x8  __attribute__((ext_vector_type(8)));
typedef unsigned short  ushort8 __attribute__((ext_vector_type(8)));
typedef float           f32x4   __attribute__((ext_vector_type(4)));

__device__ __forceinline__ unsigned short f2bf(float f) {
    unsigned int u = __float_as_uint(f);
    return (unsigned short)((u + 0x7FFFu + ((u >> 16) & 1u)) >> 16);
}

#define W1_SLOTS (12*16*64)
#define W2_SLOTS (8*16*64)

// Repack w1 (384x256) / w2 (256x256) row-major fp32 -> bf16 in MFMA B-fragment
// order: slot (s,t,l) holds w[k = s*32 + (l>>4)*8 + j][n = t*16 + (l&15)], j=0..7.
__global__ void prep_weights(const float* __restrict__ w1, const float* __restrict__ w2,
                             unsigned short* __restrict__ w1f, unsigned short* __restrict__ w2f) {
    int id = blockIdx.x * 256 + threadIdx.x;
    const float* src; unsigned short* dst; int slot;
    if (id < W1_SLOTS)                { src = w1; dst = w1f; slot = id; }
    else if (id < W1_SLOTS + W2_SLOTS){ src = w2; dst = w2f; slot = id - W1_SLOTS; }
    else return;
    int l  = slot & 63;
    int t  = (slot >> 6) & 15;
    int s  = slot >> 10;
    int k0 = s*32 + ((l >> 4) << 3);
    int n  = t*16 + (l & 15);
    unsigned short* d = dst + (size_t)slot * 8;
    #pragma unroll
    for (int j = 0; j < 8; ++j) d[j] = f2bf(src[(size_t)(k0 + j) * 256 + n]);
}

__global__ __launch_bounds__(256, 2) void courier_main(
    const float* __restrict__ xy,   const float* __restrict__ tin,
    const float* __restrict__ w_sx, const float* __restrict__ b_sx,
    const float* __restrict__ w_cx, const float* __restrict__ b_cx,
    const float* __restrict__ w_sy, const float* __restrict__ b_sy,
    const float* __restrict__ w_cy, const float* __restrict__ b_cy,
    const float* __restrict__ w_t,  const float* __restrict__ b_t,
    const unsigned short* __restrict__ w1f, const float* __restrict__ b1,
    const unsigned short* __restrict__ w2f, const float* __restrict__ b2,
    float* __restrict__ out)
{
    __shared__ __align__(16) unsigned short stage[8192];    // 16 KB: one k-step weight chunk
    __shared__ __align__(16) unsigned short h1s[128*256];   // 64 KB: h1 bf16, XOR-swizzled granules

    const int tid  = threadIdx.x;
    const int lane = tid & 63;
    const int wv   = tid >> 6;     // wave 0..3; wave covers rows [wv*32, wv*32+32)
    const int l15  = lane & 15;
    const int lq   = lane >> 4;    // quad 0..3
    const int rowblk = blockIdx.x * 128;

    // per-lane coords for its two M-tiles (row = wv*32 + mtile*16 + l15)
    const int r0 = wv*32 + l15;
    const int r1 = r0 + 16;
    const float x0 = xy[(size_t)(rowblk + r0)*2 + 0];
    const float y0 = xy[(size_t)(rowblk + r0)*2 + 1];
    const float t0 = tin[rowblk + r0];
    const float x1 = xy[(size_t)(rowblk + r1)*2 + 0];
    const float y1 = xy[(size_t)(rowblk + r1)*2 + 1];
    const float t1 = tin[rowblk + r1];

    f32x4 acc[2][16];
    #pragma unroll
    for (int m=0;m<2;++m)
      #pragma unroll
      for (int n=0;n<16;++n)
        #pragma unroll
        for (int i=0;i<4;++i) acc[m][n][i] = 0.0f;

    // ---------------- layer 1: h(384) @ w1 -> 256, A-frags computed on the fly ----
    for (int s = 0; s < 12; ++s) {
        __syncthreads();                       // staging buffer reuse guard
        bf16x8 stg[4];
        const bf16x8* gsrc = (const bf16x8*)(w1f + (size_t)s * 8192);
        #pragma unroll
        for (int j=0;j<4;++j) stg[j] = gsrc[j*256 + tid];

        // embedding A-fragments: k = s*32 + lq*8 + j  (overlaps the global loads)
        bf16x8 a0, a1;
        {
            const int kl = s*32 + lq*8;
            ushort8 u0, u1;
            if (s < 8) {                       // sin/cos segments (64-aligned, s-uniform)
                const int seg = s >> 1;        // 0:sinx 1:cosx 2:siny 3:cosy
                const float* wp = (seg==0)?w_sx:(seg==1)?w_cx:(seg==2)?w_sy:w_cy;
                const float* bp = (seg==0)?b_sx:(seg==1)?b_cx:(seg==2)?b_sy:b_cy;
                const float c0 = (seg<2)?x0:y0;
                const float c1 = (seg<2)?x1:y1;
                const int o = kl & 63;
                f32x4 wa = *(const f32x4*)(wp+o), wb = *(const f32x4*)(wp+o+4);
                f32x4 ba = *(const f32x4*)(bp+o), bb = *(const f32x4*)(bp+o+4);
                #pragma unroll
                for (int j=0;j<8;++j) {
                    float wvv = (j<4)?wa[j]:wb[j-4];
                    float bvv = (j<4)?ba[j]:bb[j-4];
                    float th0 = c0*wvv + bvv;
                    float th1 = c1*wvv + bvv;
                    float v0, v1;
                    if ((s & 2) == 0) { v0 = __sinf(th0); v1 = __sinf(th1); }
                    else              { v0 = __cosf(th0); v1 = __cosf(th1); }
                    u0[j] = f2bf(v0); u1[j] = f2bf(v1);
                }
            } else {                           // time embedding, k in [256,384)
                const int o = kl - 256;
                f32x4 wa = *(const f32x4*)(w_t+o), wb = *(const f32x4*)(w_t+o+4);
                f32x4 ba = *(const f32x4*)(b_t+o), bb = *(const f32x4*)(b_t+o+4);
                #pragma unroll
                for (int j=0;j<8;++j) {
                    float wvv = (j<4)?wa[j]:wb[j-4];
                    float bvv = (j<4)?ba[j]:bb[j-4];
                    float th0 = t0*wvv + bvv;
                    float th1 = t1*wvv + bvv;
                    u0[j] = f2bf(fmaxf(th0, 0.01f*th0));
                    u1[j] = f2bf(fmaxf(th1, 0.01f*th1));
                }
            }
            a0 = __builtin_bit_cast(bf16x8, u0);
            a1 = __builtin_bit_cast(bf16x8, u1);
        }

        bf16x8* sdst = (bf16x8*)stage;
        #pragma unroll
        for (int j=0;j<4;++j) sdst[j*256 + tid] = stg[j];
        __syncthreads();

        const bf16x8* sb = (const bf16x8*)stage;
        #pragma unroll
        for (int n=0;n<16;++n) {
            bf16x8 bfr = sb[n*64 + lane];
            acc[0][n] = __builtin_amdgcn_mfma_f32_16x16x32_bf16(a0, bfr, acc[0][n], 0,0,0);
            acc[1][n] = __builtin_amdgcn_mfma_f32_16x16x32_bf16(a1, bfr, acc[1][n], 0,0,0);
        }
    }

    // ---------------- epilogue 1: h1 = leaky(acc+b1) -> bf16 LDS (swizzled) -------
    // C layout: col = l15 (+16*n), row = lq*4 + rg (+16*m + 32*wv)
    #pragma unroll
    for (int m=0;m<2;++m) {
        const int rb = wv*32 + m*16 + lq*4;
        #pragma unroll
        for (int n=0;n<16;++n) {
            const int c = n*16 + l15;
            const float bv = b1[c];
            const int g = c >> 3;
            #pragma unroll
            for (int rg=0; rg<4; ++rg) {
                const int r = rb + rg;
                float v = acc[m][n][rg] + bv;
                v = fmaxf(v, 0.01f*v);
                h1s[r*256 + ((g ^ (r & 7)) << 3) + (c & 7)] = f2bf(v);
            }
        }
    }

    #pragma unroll
    for (int m=0;m<2;++m)
      #pragma unroll
      for (int n=0;n<16;++n)
        #pragma unroll
        for (int i=0;i<4;++i) acc[m][n][i] = 0.0f;

    // ---------------- layer 2: h1(256) @ w2 -> 256, A-frags from swizzled LDS -----
    for (int s = 0; s < 8; ++s) {
        __syncthreads();                       // also guards h1s writes on s==0
        bf16x8 stg[4];
        const bf16x8* gsrc = (const bf16x8*)(w2f + (size_t)s * 8192);
        #pragma unroll
        for (int j=0;j<4;++j) stg[j] = gsrc[j*256 + tid];

        const int g0  = s*4 + lq;              // k-granule: k = s*32 + lq*8
        const int rA0 = wv*32 + l15;
        const int rA1 = rA0 + 16;
        bf16x8 a0 = *(const bf16x8*)&h1s[rA0*256 + ((g0 ^ (rA0 & 7)) << 3)];
        bf16x8 a1 = *(const bf16x8*)&h1s[rA1*256 + ((g0 ^ (rA1 & 7)) << 3)];

        bf16x8* sdst = (bf16x8*)stage;
        #pragma unroll
        for (int j=0;j<4;++j) sdst[j*256 + tid] = stg[j];
        __syncthreads();

        const bf16x8* sb = (const bf16x8*)stage;
        #pragma unroll
        for (int n=0;n<16;++n) {
            bf16x8 bfr = sb[n*64 + lane];
            acc[0][n] = __builtin_amdgcn_mfma_f32_16x16x32_bf16(a0, bfr, acc[0][n], 0,0,0);
            acc[1][n] = __builtin_amdgcn_mfma_f32_16x16x32_bf16(a1, bfr, acc[1][n], 0,0,0);
        }
    }

    // ---------------- epilogue 2: out = leaky(acc+b2), fp32 ------------------------
    #pragma unroll
    for (int m=0;m<2;++m) {
        const int rb = wv*32 + m*16 + lq*4;
        #pragma unroll
        for (int n=0;n<16;++n) {
            const int c = n*16 + l15;
            const float bv = b2[c];
            #pragma unroll
            for (int rg=0; rg<4; ++rg) {
                float v = acc[m][n][rg] + bv;
                v = fmaxf(v, 0.01f*v);
                out[(size_t)(rowblk + rb + rg)*256 + c] = v;
            }
        }
    }
}

extern "C" void kernel_launch(void* const* d_in, const int* in_sizes, int n_in,
                              void* d_out, int out_size, void* d_ws, size_t ws_size,
                              hipStream_t stream) {
    const float* xy   = (const float*)d_in[0];
    const float* tin  = (const float*)d_in[1];
    const float* w_sx = (const float*)d_in[2];
    const float* b_sx = (const float*)d_in[3];
    const float* w_cx = (const float*)d_in[4];
    const float* b_cx = (const float*)d_in[5];
    const float* w_sy = (const float*)d_in[6];
    const float* b_sy = (const float*)d_in[7];
    const float* w_cy = (const float*)d_in[8];
    const float* b_cy = (const float*)d_in[9];
    const float* w_t  = (const float*)d_in[10];
    const float* b_t  = (const float*)d_in[11];
    const float* w1   = (const float*)d_in[12];
    const float* b1   = (const float*)d_in[13];
    const float* w2   = (const float*)d_in[14];
    const float* b2   = (const float*)d_in[15];

    unsigned short* w1f = (unsigned short*)d_ws;        // 12*16*64*8 ushorts = 196608 B
    unsigned short* w2f = w1f + (size_t)W1_SLOTS * 8;   // 131072 B

    prep_weights<<<(W1_SLOTS + W2_SLOTS + 255)/256, 256, 0, stream>>>(w1, w2, w1f, w2f);
    courier_main<<<262144/128, 256, 0, stream>>>(xy, tin, w_sx,b_sx,w_cx,b_cx,
                                                 w_sy,b_sy,w_cy,b_cy,w_t,b_t,
                                                 w1f, b1, w2f, b2, (float*)d_out);
}